// Round 2
// baseline (194.601 us; speedup 1.0000x reference)
//
#include <hip/hip_runtime.h>

// SymmetricContraction: out[n,c,i] = cubic polynomial in x[n,c,:] with
// species/channel-dependent coefficients (968 sorted monomials, D=16).
// Pipeline (3 dispatches):
//   zero_setup : zero out + species-bucket atoms (block 128 does setup)
//   coef_kernel: coef[s,t,c,0:4] = mult * sum_k u[t,k,i] w[s,k,c]  (~20 MB in ws)
//   contract   : per (atom,channel) evaluate 968-term polynomial, 4 atoms/thread
// ws requirement: ~19.9 MiB.

#define DD     16
#define NATOM  512
#define NCH    128
#define NSPEC  10
#define NT3    816
#define NT2    136
#define NT1    16
#define NT     968
#define ATB    16    // atoms per eval block (same species)
#define APT    4     // atoms per thread
#define MAXB   48    // >= sum_s ceil(cnt_s/ATB)  (<= 512/16 + 10 = 42)
#define CHUNKS 8
#define CHALF  2     // channel halves (64 ch per block)

#define WS_DESC  0
#define WS_ORDER 1024
#define WS_COEF  8192
// coef: NSPEC*NT*NCH*4 floats = 19,824,640 bytes

// ---------------- zero + setup (fused) ----------------
__global__ __launch_bounds__(512) void zero_setup_kernel(const int* __restrict__ index,
                                                         int* __restrict__ desc,
                                                         int* __restrict__ order,
                                                         float4* __restrict__ out) {
  if (blockIdx.x < 128) {
    out[blockIdx.x * 512 + threadIdx.x] = float4{0.f, 0.f, 0.f, 0.f};
    return;
  }
  // block 128: species bucketing of atoms, padded to ATB
  __shared__ int cnt[NSPEC], cursor[NSPEC], nb[NSPEC], bbase[NSPEC];
  const int tid = threadIdx.x;
  if (tid < NSPEC) { cnt[tid] = 0; cursor[tid] = 0; }
  __syncthreads();
  if (tid < NATOM) atomicAdd(&cnt[index[tid]], 1);
  for (int i = tid; i < MAXB * ATB; i += 512) order[i] = -1;
  __syncthreads();
  if (tid == 0) {
    int base = 0;
    for (int s = 0; s < NSPEC; s++) {
      nb[s] = (cnt[s] + ATB - 1) / ATB;
      bbase[s] = base;
      base += nb[s];
    }
  }
  __syncthreads();
  if (tid < NATOM) {
    int s = index[tid];
    int pos = atomicAdd(&cursor[s], 1);
    order[bbase[s] * ATB + pos] = tid;
  }
  if (tid < MAXB) {
    int sp = -1;
    for (int s = 0; s < NSPEC; s++)
      if (tid >= bbase[s] && tid < bbase[s] + nb[s]) sp = s;
    desc[tid] = sp;
  }
}

// ---------------- term decode (pure combinatorics, D=16) ----------------
__device__ __forceinline__ void decode_term(int t, int& kind, int& a, int& b,
                                            int& j, int& mult) {
  a = 0; b = 0; j = 0;
  if (t < NT3) {
    kind = 3;
    int r = t;
    for (a = 0; a < DD; a++) { int ca = (DD - a) * (DD - a + 1) / 2; if (r < ca) break; r -= ca; }
    for (b = a; b < DD; b++) { int cb = DD - b; if (r < cb) break; r -= cb; }
    j = b + r;
    mult = (a == b && b == j) ? 1 : ((a == b || b == j) ? 3 : 6);
  } else if (t < NT3 + NT2) {
    kind = 2;
    int r = t - NT3;
    for (a = 0; a < DD; a++) { int ca = DD - a; if (r < ca) break; r -= ca; }
    b = a + r;
    mult = (a == b) ? 1 : 2;
  } else {
    kind = 1; a = t - NT3 - NT2; mult = 1;
  }
}

// ---------------- coefficient build ----------------
__global__ __launch_bounds__(128) void coef_kernel(
    const float* __restrict__ u3_0, const float* __restrict__ w3_0,
    const float* __restrict__ u2_0, const float* __restrict__ w2_0,
    const float* __restrict__ u1_0, const float* __restrict__ w1_0,
    const float* __restrict__ u3_1, const float* __restrict__ w3_1,
    const float* __restrict__ u2_1, const float* __restrict__ w2_1,
    const float* __restrict__ u1_1, const float* __restrict__ w1_1,
    float* __restrict__ coef) {
  const int s = blockIdx.x;
  const int c = threadIdx.x;
  const int tbase = blockIdx.y * 8;

  float r3_0[23], r3_1[33], r2_0[4], r2_1[6];
#pragma unroll
  for (int k = 0; k < 23; k++) r3_0[k] = w3_0[(s * 23 + k) * NCH + c];
#pragma unroll
  for (int k = 0; k < 33; k++) r3_1[k] = w3_1[(s * 33 + k) * NCH + c];
#pragma unroll
  for (int k = 0; k < 4; k++) r2_0[k] = w2_0[(s * 4 + k) * NCH + c];
#pragma unroll
  for (int k = 0; k < 6; k++) r2_1[k] = w2_1[(s * 6 + k) * NCH + c];
  const float r1_0 = w1_0[s * NCH + c];
  const float r1_1 = w1_1[s * NCH + c];

  for (int tt = 0; tt < 8; tt++) {
    const int t = tbase + tt;
    int kind, a, b, j, mult;
    decode_term(t, kind, a, b, j, mult);
    float s0 = 0.f, s1 = 0.f, s2 = 0.f, s3 = 0.f;
    if (kind == 3) {
      const float* u0p = u3_0 + ((a * DD + b) * DD + j) * 23;
#pragma unroll
      for (int k = 0; k < 23; k++) s0 += u0p[k] * r3_0[k];
      const float* u1p = u3_1 + ((size_t)((a * DD + b) * DD + j)) * 99;
#pragma unroll
      for (int k = 0; k < 33; k++) {
        const float w = r3_1[k];
        s1 += u1p[k * 3 + 0] * w;
        s2 += u1p[k * 3 + 1] * w;
        s3 += u1p[k * 3 + 2] * w;
      }
    } else if (kind == 2) {
      const float* u0p = u2_0 + (a * DD + b) * 4;
#pragma unroll
      for (int k = 0; k < 4; k++) s0 += u0p[k] * r2_0[k];
      const float* u1p = u2_1 + (a * DD + b) * 18;
#pragma unroll
      for (int k = 0; k < 6; k++) {
        const float w = r2_1[k];
        s1 += u1p[k * 3 + 0] * w;
        s2 += u1p[k * 3 + 1] * w;
        s3 += u1p[k * 3 + 2] * w;
      }
    } else {
      s0 = u1_0[a] * r1_0;
      s1 = u1_1[a * 3 + 0] * r1_1;
      s2 = u1_1[a * 3 + 1] * r1_1;
      s3 = u1_1[a * 3 + 2] * r1_1;
    }
    const float fm = (float)mult;
    float4 cf{fm * s0, fm * s1, fm * s2, fm * s3};
    *(float4*)(coef + ((size_t)(s * NT + t) * NCH + c) * 4) = cf;
  }
}

// ---------------- polynomial evaluation ----------------
template <int T0, int T1>
__device__ __forceinline__ void accum_chunk(const float* __restrict__ cp,
                                            const float (&xr)[APT][DD],
                                            float (&ac)[APT][4]) {
  int t = 0;
  // cubic terms: a<=b<=j
#pragma unroll
  for (int a = 0; a < DD; a++)
#pragma unroll
    for (int b = a; b < DD; b++) {
      float pp[APT];
#pragma unroll
      for (int k = 0; k < APT; k++) pp[k] = xr[k][a] * xr[k][b];
#pragma unroll
      for (int j = b; j < DD; j++) {
        if (t >= T0 && t < T1) {
          const float4 cf = *(const float4*)(cp + (size_t)t * (NCH * 4));
#pragma unroll
          for (int k = 0; k < APT; k++) {
            const float m = pp[k] * xr[k][j];
            ac[k][0] += cf.x * m; ac[k][1] += cf.y * m;
            ac[k][2] += cf.z * m; ac[k][3] += cf.w * m;
          }
        }
        ++t;
      }
    }
  // pair terms: a<=b
#pragma unroll
  for (int a = 0; a < DD; a++)
#pragma unroll
    for (int b = a; b < DD; b++) {
      if (t >= T0 && t < T1) {
        const float4 cf = *(const float4*)(cp + (size_t)t * (NCH * 4));
#pragma unroll
        for (int k = 0; k < APT; k++) {
          const float m = xr[k][a] * xr[k][b];
          ac[k][0] += cf.x * m; ac[k][1] += cf.y * m;
          ac[k][2] += cf.z * m; ac[k][3] += cf.w * m;
        }
      }
      ++t;
    }
  // linear terms
#pragma unroll
  for (int a = 0; a < DD; a++) {
    if (t >= T0 && t < T1) {
      const float4 cf = *(const float4*)(cp + (size_t)t * (NCH * 4));
#pragma unroll
      for (int k = 0; k < APT; k++) {
        const float m = xr[k][a];
        ac[k][0] += cf.x * m; ac[k][1] += cf.y * m;
        ac[k][2] += cf.z * m; ac[k][3] += cf.w * m;
      }
    }
    ++t;
  }
}

__device__ __forceinline__ void load16(float (&xr)[DD], const float* __restrict__ p) {
  const float4* q = (const float4*)p;
  const float4 v0 = q[0], v1 = q[1], v2 = q[2], v3 = q[3];
  xr[0] = v0.x; xr[1] = v0.y; xr[2] = v0.z; xr[3] = v0.w;
  xr[4] = v1.x; xr[5] = v1.y; xr[6] = v1.z; xr[7] = v1.w;
  xr[8] = v2.x; xr[9] = v2.y; xr[10] = v2.z; xr[11] = v2.w;
  xr[12] = v3.x; xr[13] = v3.y; xr[14] = v3.z; xr[15] = v3.w;
}

__global__ __launch_bounds__(256, 4) void contract_kernel(const float* __restrict__ x,
                                                          const int* __restrict__ desc,
                                                          const int* __restrict__ order,
                                                          const float* __restrict__ coef,
                                                          float* __restrict__ out) {
  const int s = desc[blockIdx.x];
  if (s < 0) return;
  const int cl = threadIdx.x & 63;
  const int g  = threadIdx.x >> 6;            // 0..3 -> atoms 4g..4g+3
  const int c  = blockIdx.z * 64 + cl;

  int n[APT];
#pragma unroll
  for (int k = 0; k < APT; k++) n[k] = order[blockIdx.x * ATB + g * APT + k];

  float xr[APT][DD];
#pragma unroll
  for (int k = 0; k < APT; k++)
#pragma unroll
    for (int i = 0; i < DD; i++) xr[k][i] = 0.f;
#pragma unroll
  for (int k = 0; k < APT; k++)
    if (n[k] >= 0) load16(xr[k], x + ((size_t)n[k] * NCH + c) * DD);

  float ac[APT][4];
#pragma unroll
  for (int k = 0; k < APT; k++) { ac[k][0] = 0.f; ac[k][1] = 0.f; ac[k][2] = 0.f; ac[k][3] = 0.f; }

  const float* cp = coef + (size_t)s * (NT * NCH * 4) + (size_t)c * 4;

  switch (blockIdx.y) {
    case 0: accum_chunk<0, 121>(cp, xr, ac); break;
    case 1: accum_chunk<121, 242>(cp, xr, ac); break;
    case 2: accum_chunk<242, 363>(cp, xr, ac); break;
    case 3: accum_chunk<363, 484>(cp, xr, ac); break;
    case 4: accum_chunk<484, 605>(cp, xr, ac); break;
    case 5: accum_chunk<605, 726>(cp, xr, ac); break;
    case 6: accum_chunk<726, 847>(cp, xr, ac); break;
    default: accum_chunk<847, 968>(cp, xr, ac); break;
  }

#pragma unroll
  for (int k = 0; k < APT; k++)
    if (n[k] >= 0) {
      float* o = out + ((size_t)n[k] * NCH + c) * 4;
      atomicAdd(o + 0, ac[k][0]); atomicAdd(o + 1, ac[k][1]);
      atomicAdd(o + 2, ac[k][2]); atomicAdd(o + 3, ac[k][3]);
    }
}

extern "C" void kernel_launch(void* const* d_in, const int* in_sizes, int n_in,
                              void* d_out, int out_size, void* d_ws, size_t ws_size,
                              hipStream_t stream) {
  const float* x    = (const float*)d_in[0];
  const int* index  = (const int*)d_in[1];
  const float* u3_0 = (const float*)d_in[2];
  const float* w3_0 = (const float*)d_in[3];
  const float* u2_0 = (const float*)d_in[4];
  const float* w2_0 = (const float*)d_in[5];
  const float* u1_0 = (const float*)d_in[6];
  const float* w1_0 = (const float*)d_in[7];
  const float* u3_1 = (const float*)d_in[8];
  const float* w3_1 = (const float*)d_in[9];
  const float* u2_1 = (const float*)d_in[10];
  const float* w2_1 = (const float*)d_in[11];
  const float* u1_1 = (const float*)d_in[12];
  const float* w1_1 = (const float*)d_in[13];
  float* out = (float*)d_out;

  char* ws = (char*)d_ws;
  int* desc   = (int*)(ws + WS_DESC);
  int* order  = (int*)(ws + WS_ORDER);
  float* coef = (float*)(ws + WS_COEF);

  zero_setup_kernel<<<129, 512, 0, stream>>>(index, desc, order, (float4*)out);
  coef_kernel<<<dim3(NSPEC, NT / 8), 128, 0, stream>>>(
      u3_0, w3_0, u2_0, w2_0, u1_0, w1_0,
      u3_1, w3_1, u2_1, w2_1, u1_1, w1_1, coef);
  contract_kernel<<<dim3(MAXB, CHUNKS, CHALF), 256, 0, stream>>>(x, desc, order, coef, out);
}

// Round 3
// 187.456 us; speedup vs baseline: 1.0381x; 1.0381x over previous
//
#include <hip/hip_runtime.h>

// SymmetricContraction: out[n,c,i] = cubic polynomial in x[n,c,:] with
// species/channel-dependent coefficients (968 sorted monomials, D=16).
// Pipeline (4 dispatches, no atomics):
//   setup     : species-bucket atoms into ATB-padded blocks
//   coef      : coef[s,t,c,0:4] = mult * sum_k u[t,k,i] w[s,k,c]   (~20 MB ws)
//   contract  : per (atomblk, term-chunk, ch-half) eval -> disjoint partials
//   reduce    : out = sum over 16 chunk partials
// ws requirement: ~35 MiB.

#define DD     16
#define NATOM  512
#define NCH    128
#define NSPEC  10
#define NT3    816
#define NT2    136
#define NT     968
#define ATB    8     // atoms per eval block (same species)
#define APT    2     // atoms per thread
#define MAXB   74    // >= sum_s ceil(cnt_s/ATB)
#define CHUNKS 16
#define CHALF  2     // channel halves (64 ch per block)

#define WS_DESC  0
#define WS_ORDER 1024
#define WS_COEF  8192
#define COEF_BYTES (NSPEC * NT * NCH * 16)        // 19,824,640
#define WS_PART  (WS_COEF + COEF_BYTES)           // partials: CHUNKS*1MB = 16 MB

// ---------------- setup: species bucketing ----------------
__global__ __launch_bounds__(512) void setup_kernel(const int* __restrict__ index,
                                                    int* __restrict__ desc,
                                                    int* __restrict__ order) {
  __shared__ int cnt[NSPEC], cursor[NSPEC], nb[NSPEC], bbase[NSPEC];
  const int tid = threadIdx.x;
  if (tid < NSPEC) { cnt[tid] = 0; cursor[tid] = 0; }
  __syncthreads();
  if (tid < NATOM) atomicAdd(&cnt[index[tid]], 1);
  for (int i = tid; i < MAXB * ATB; i += 512) order[i] = -1;
  __syncthreads();
  if (tid == 0) {
    int base = 0;
    for (int s = 0; s < NSPEC; s++) {
      nb[s] = (cnt[s] + ATB - 1) / ATB;
      bbase[s] = base;
      base += nb[s];
    }
  }
  __syncthreads();
  if (tid < NATOM) {
    int s = index[tid];
    int pos = atomicAdd(&cursor[s], 1);
    order[bbase[s] * ATB + pos] = tid;
  }
  if (tid < MAXB) {
    int sp = -1;
    for (int s = 0; s < NSPEC; s++)
      if (tid >= bbase[s] && tid < bbase[s] + nb[s]) sp = s;
    desc[tid] = sp;
  }
}

// ---------------- term decode (pure combinatorics, D=16) ----------------
__device__ __forceinline__ void decode_term(int t, int& kind, int& a, int& b,
                                            int& j, int& mult) {
  a = 0; b = 0; j = 0;
  if (t < NT3) {
    kind = 3;
    int r = t;
    for (a = 0; a < DD; a++) { int ca = (DD - a) * (DD - a + 1) / 2; if (r < ca) break; r -= ca; }
    for (b = a; b < DD; b++) { int cb = DD - b; if (r < cb) break; r -= cb; }
    j = b + r;
    mult = (a == b && b == j) ? 1 : ((a == b || b == j) ? 3 : 6);
  } else if (t < NT3 + NT2) {
    kind = 2;
    int r = t - NT3;
    for (a = 0; a < DD; a++) { int ca = DD - a; if (r < ca) break; r -= ca; }
    b = a + r;
    mult = (a == b) ? 1 : 2;
  } else {
    kind = 1; a = t - NT3 - NT2; mult = 1;
  }
}

// ---------------- coefficient build (4 terms / block) ----------------
__global__ __launch_bounds__(128) void coef_kernel(
    const float* __restrict__ u3_0, const float* __restrict__ w3_0,
    const float* __restrict__ u2_0, const float* __restrict__ w2_0,
    const float* __restrict__ u1_0, const float* __restrict__ w1_0,
    const float* __restrict__ u3_1, const float* __restrict__ w3_1,
    const float* __restrict__ u2_1, const float* __restrict__ w2_1,
    const float* __restrict__ u1_1, const float* __restrict__ w1_1,
    float* __restrict__ coef) {
  const int s = blockIdx.x;
  const int c = threadIdx.x;
  const int tbase = blockIdx.y * 4;

  float r3_0[23], r3_1[33], r2_0[4], r2_1[6];
#pragma unroll
  for (int k = 0; k < 23; k++) r3_0[k] = w3_0[(s * 23 + k) * NCH + c];
#pragma unroll
  for (int k = 0; k < 33; k++) r3_1[k] = w3_1[(s * 33 + k) * NCH + c];
#pragma unroll
  for (int k = 0; k < 4; k++) r2_0[k] = w2_0[(s * 4 + k) * NCH + c];
#pragma unroll
  for (int k = 0; k < 6; k++) r2_1[k] = w2_1[(s * 6 + k) * NCH + c];
  const float r1_0 = w1_0[s * NCH + c];
  const float r1_1 = w1_1[s * NCH + c];

  for (int tt = 0; tt < 4; tt++) {
    const int t = tbase + tt;
    int kind, a, b, j, mult;
    decode_term(t, kind, a, b, j, mult);
    float s0 = 0.f, s1 = 0.f, s2 = 0.f, s3 = 0.f;
    if (kind == 3) {
      const float* u0p = u3_0 + ((a * DD + b) * DD + j) * 23;
#pragma unroll
      for (int k = 0; k < 23; k++) s0 += u0p[k] * r3_0[k];
      const float* u1p = u3_1 + ((size_t)((a * DD + b) * DD + j)) * 99;
#pragma unroll
      for (int k = 0; k < 33; k++) {
        const float w = r3_1[k];
        s1 += u1p[k * 3 + 0] * w;
        s2 += u1p[k * 3 + 1] * w;
        s3 += u1p[k * 3 + 2] * w;
      }
    } else if (kind == 2) {
      const float* u0p = u2_0 + (a * DD + b) * 4;
#pragma unroll
      for (int k = 0; k < 4; k++) s0 += u0p[k] * r2_0[k];
      const float* u1p = u2_1 + (a * DD + b) * 18;
#pragma unroll
      for (int k = 0; k < 6; k++) {
        const float w = r2_1[k];
        s1 += u1p[k * 3 + 0] * w;
        s2 += u1p[k * 3 + 1] * w;
        s3 += u1p[k * 3 + 2] * w;
      }
    } else {
      s0 = u1_0[a] * r1_0;
      s1 = u1_1[a * 3 + 0] * r1_1;
      s2 = u1_1[a * 3 + 1] * r1_1;
      s3 = u1_1[a * 3 + 2] * r1_1;
    }
    const float fm = (float)mult;
    float4 cf{fm * s0, fm * s1, fm * s2, fm * s3};
    *(float4*)(coef + ((size_t)(s * NT + t) * NCH + c) * 4) = cf;
  }
}

// ---------------- polynomial evaluation ----------------
template <int T0, int T1>
__device__ __forceinline__ void accum_chunk(const float* __restrict__ cp,
                                            const float (&xr)[APT][DD],
                                            float (&ac)[APT][4]) {
  int t = 0;
  // cubic: a<=b<=j
#pragma unroll
  for (int a = 0; a < DD; a++)
#pragma unroll
    for (int b = a; b < DD; b++) {
      float pp[APT];
#pragma unroll
      for (int k = 0; k < APT; k++) pp[k] = xr[k][a] * xr[k][b];
#pragma unroll
      for (int j = b; j < DD; j++) {
        if (t >= T0 && t < T1) {
          const float4 cf = *(const float4*)(cp + (size_t)t * (NCH * 4));
#pragma unroll
          for (int k = 0; k < APT; k++) {
            const float m = pp[k] * xr[k][j];
            ac[k][0] += cf.x * m; ac[k][1] += cf.y * m;
            ac[k][2] += cf.z * m; ac[k][3] += cf.w * m;
          }
        }
        ++t;
      }
    }
  // pair: a<=b
#pragma unroll
  for (int a = 0; a < DD; a++)
#pragma unroll
    for (int b = a; b < DD; b++) {
      if (t >= T0 && t < T1) {
        const float4 cf = *(const float4*)(cp + (size_t)t * (NCH * 4));
#pragma unroll
        for (int k = 0; k < APT; k++) {
          const float m = xr[k][a] * xr[k][b];
          ac[k][0] += cf.x * m; ac[k][1] += cf.y * m;
          ac[k][2] += cf.z * m; ac[k][3] += cf.w * m;
        }
      }
      ++t;
    }
  // linear
#pragma unroll
  for (int a = 0; a < DD; a++) {
    if (t >= T0 && t < T1) {
      const float4 cf = *(const float4*)(cp + (size_t)t * (NCH * 4));
#pragma unroll
      for (int k = 0; k < APT; k++) {
        const float m = xr[k][a];
        ac[k][0] += cf.x * m; ac[k][1] += cf.y * m;
        ac[k][2] += cf.z * m; ac[k][3] += cf.w * m;
      }
    }
    ++t;
  }
}

__device__ __forceinline__ void load16(float (&xr)[DD], const float* __restrict__ p) {
  const float4* q = (const float4*)p;
  const float4 v0 = q[0], v1 = q[1], v2 = q[2], v3 = q[3];
  xr[0] = v0.x; xr[1] = v0.y; xr[2] = v0.z; xr[3] = v0.w;
  xr[4] = v1.x; xr[5] = v1.y; xr[6] = v1.z; xr[7] = v1.w;
  xr[8] = v2.x; xr[9] = v2.y; xr[10] = v2.z; xr[11] = v2.w;
  xr[12] = v3.x; xr[13] = v3.y; xr[14] = v3.z; xr[15] = v3.w;
}

constexpr int chunk_t0(int k) { return k * 60 + (k < 8 ? k : 8); }  // 8x61 + 8x60 = 968

__global__ __launch_bounds__(256, 4) void contract_kernel(const float* __restrict__ x,
                                                          const int* __restrict__ desc,
                                                          const int* __restrict__ order,
                                                          const float* __restrict__ coef,
                                                          float* __restrict__ partial) {
  const int s = desc[blockIdx.x];
  if (s < 0) return;
  const int cl = threadIdx.x & 63;
  const int g  = threadIdx.x >> 6;            // 0..3 -> atoms 2g, 2g+1
  const int c  = blockIdx.z * 64 + cl;

  int n[APT];
#pragma unroll
  for (int k = 0; k < APT; k++) n[k] = order[blockIdx.x * ATB + g * APT + k];

  float xr[APT][DD];
#pragma unroll
  for (int k = 0; k < APT; k++)
#pragma unroll
    for (int i = 0; i < DD; i++) xr[k][i] = 0.f;
#pragma unroll
  for (int k = 0; k < APT; k++)
    if (n[k] >= 0) load16(xr[k], x + ((size_t)n[k] * NCH + c) * DD);

  float ac[APT][4];
#pragma unroll
  for (int k = 0; k < APT; k++) { ac[k][0] = 0.f; ac[k][1] = 0.f; ac[k][2] = 0.f; ac[k][3] = 0.f; }

  const float* cp = coef + (size_t)s * (NT * NCH * 4) + (size_t)c * 4;

#define CHUNK_CASE(K) case K: accum_chunk<chunk_t0(K), chunk_t0(K + 1)>(cp, xr, ac); break;
  switch (blockIdx.y) {
    CHUNK_CASE(0)  CHUNK_CASE(1)  CHUNK_CASE(2)  CHUNK_CASE(3)
    CHUNK_CASE(4)  CHUNK_CASE(5)  CHUNK_CASE(6)  CHUNK_CASE(7)
    CHUNK_CASE(8)  CHUNK_CASE(9)  CHUNK_CASE(10) CHUNK_CASE(11)
    CHUNK_CASE(12) CHUNK_CASE(13) CHUNK_CASE(14)
    default: accum_chunk<chunk_t0(15), chunk_t0(16)>(cp, xr, ac); break;
  }
#undef CHUNK_CASE

  float* pb = partial + (size_t)blockIdx.y * (NATOM * NCH * 4);
#pragma unroll
  for (int k = 0; k < APT; k++)
    if (n[k] >= 0)
      *(float4*)(pb + ((size_t)n[k] * NCH + c) * 4) =
          float4{ac[k][0], ac[k][1], ac[k][2], ac[k][3]};
}

// ---------------- final reduction over chunks ----------------
__global__ __launch_bounds__(256) void reduce_kernel(const float4* __restrict__ partial,
                                                     float4* __restrict__ out) {
  const int i = blockIdx.x * 256 + threadIdx.x;  // 0 .. NATOM*NCH-1
  float4 s{0.f, 0.f, 0.f, 0.f};
#pragma unroll
  for (int ch = 0; ch < CHUNKS; ch++) {
    const float4 v = partial[(size_t)ch * (NATOM * NCH) + i];
    s.x += v.x; s.y += v.y; s.z += v.z; s.w += v.w;
  }
  out[i] = s;
}

extern "C" void kernel_launch(void* const* d_in, const int* in_sizes, int n_in,
                              void* d_out, int out_size, void* d_ws, size_t ws_size,
                              hipStream_t stream) {
  const float* x    = (const float*)d_in[0];
  const int* index  = (const int*)d_in[1];
  const float* u3_0 = (const float*)d_in[2];
  const float* w3_0 = (const float*)d_in[3];
  const float* u2_0 = (const float*)d_in[4];
  const float* w2_0 = (const float*)d_in[5];
  const float* u1_0 = (const float*)d_in[6];
  const float* w1_0 = (const float*)d_in[7];
  const float* u3_1 = (const float*)d_in[8];
  const float* w3_1 = (const float*)d_in[9];
  const float* u2_1 = (const float*)d_in[10];
  const float* w2_1 = (const float*)d_in[11];
  const float* u1_1 = (const float*)d_in[12];
  const float* w1_1 = (const float*)d_in[13];
  float* out = (float*)d_out;

  char* ws = (char*)d_ws;
  int* desc     = (int*)(ws + WS_DESC);
  int* order    = (int*)(ws + WS_ORDER);
  float* coef   = (float*)(ws + WS_COEF);
  float* partial = (float*)(ws + WS_PART);

  setup_kernel<<<1, 512, 0, stream>>>(index, desc, order);
  coef_kernel<<<dim3(NSPEC, NT / 4), 128, 0, stream>>>(
      u3_0, w3_0, u2_0, w2_0, u1_0, w1_0,
      u3_1, w3_1, u2_1, w2_1, u1_1, w1_1, coef);
  contract_kernel<<<dim3(MAXB, CHUNKS, CHALF), 256, 0, stream>>>(x, desc, order, coef, partial);
  reduce_kernel<<<(NATOM * NCH) / 256, 256, 0, stream>>>((const float4*)partial, (float4*)out);
}